// Round 1
// baseline (4965.776 us; speedup 1.0000x reference)
//
#include <hip/hip_runtime.h>

#define NN 40000
#define NE 640000
#define HID 128

// out[n][m] = (relu?)( sum_k X[n][k] * W[m][k] + b[m] ), W is [128][K] row-major.
// 128 threads = one per output column m; each block does 8 rows.
template<int K, bool RELU>
__global__ __launch_bounds__(128) void lin_kernel(
    const float* __restrict__ X, const float* __restrict__ W,
    const float* __restrict__ b, float* __restrict__ out, int n_rows)
{
    constexpr int ROWS = 8;
    __shared__ float xs[ROWS * K];
    const int m  = threadIdx.x;
    const int r0 = blockIdx.x * ROWS;
    for (int i = threadIdx.x; i < ROWS * K; i += 128) {
        int r = i / K, k = i - r * K;
        int row = r0 + r;
        xs[i] = (row < n_rows) ? X[(size_t)row * K + k] : 0.f;
    }
    __syncthreads();
    float acc[ROWS] = {};
    const float* Wm = W + (size_t)m * K;
    for (int k = 0; k < K; ++k) {
        float w = Wm[k];
        #pragma unroll
        for (int r = 0; r < ROWS; ++r) acc[r] += xs[r * K + k] * w;
    }
    const float bias = b[m];
    #pragma unroll
    for (int r = 0; r < ROWS; ++r) {
        int row = r0 + r;
        if (row < n_rows) {
            float v = acc[r] + bias;
            out[(size_t)row * HID + m] = RELU ? fmaxf(v, 0.f) : v;
        }
    }
}

// Concat variant: X = [A | B] per row, K = 256, W is [128][256].
template<bool RELU>
__global__ __launch_bounds__(128) void lin_cat_kernel(
    const float* __restrict__ A, const float* __restrict__ B,
    const float* __restrict__ W, const float* __restrict__ b,
    float* __restrict__ out, int n_rows)
{
    constexpr int ROWS = 8;
    constexpr int K = 2 * HID;
    __shared__ float xs[ROWS * K];
    const int m  = threadIdx.x;
    const int r0 = blockIdx.x * ROWS;
    for (int i = threadIdx.x; i < ROWS * HID; i += 128) {
        int r = i / HID, k = i - r * HID;
        int row = r0 + r;
        float a = 0.f, bb = 0.f;
        if (row < n_rows) {
            a  = A[(size_t)row * HID + k];
            bb = B[(size_t)row * HID + k];
        }
        xs[r * K + k]       = a;
        xs[r * K + HID + k] = bb;
    }
    __syncthreads();
    float acc[ROWS] = {};
    const float* Wm = W + (size_t)m * K;
    for (int k = 0; k < K; ++k) {
        float w = Wm[k];
        #pragma unroll
        for (int r = 0; r < ROWS; ++r) acc[r] += xs[r * K + k] * w;
    }
    const float bias = b[m];
    #pragma unroll
    for (int r = 0; r < ROWS; ++r) {
        int row = r0 + r;
        if (row < n_rows) {
            float v = acc[r] + bias;
            out[(size_t)row * HID + m] = RELU ? fmaxf(v, 0.f) : v;
        }
    }
}

// agg[dst[e]][:] += h[src[e]][:]  — 32 threads per edge, float4 each.
__global__ __launch_bounds__(256) void scatter_add_kernel(
    const float* __restrict__ h, const int* __restrict__ src,
    const int* __restrict__ dst, float* __restrict__ agg)
{
    long long t = (long long)blockIdx.x * blockDim.x + threadIdx.x;
    int e  = (int)(t >> 5);
    int c4 = (int)(t & 31);
    if (e >= NE) return;
    int s = src[e], d = dst[e];
    float4 v = *(const float4*)(h + (size_t)s * HID + c4 * 4);
    float* p = agg + (size_t)d * HID + c4 * 4;
    atomicAdd(p + 0, v.x);
    atomicAdd(p + 1, v.y);
    atomicAdd(p + 2, v.z);
    atomicAdd(p + 3, v.w);
}

// out[n] = dot(h[n][:], w[:]) + b[0] — one 64-lane wave per node.
__global__ __launch_bounds__(256) void head_out_kernel(
    const float* __restrict__ h, const float* __restrict__ w,
    const float* __restrict__ b, float* __restrict__ out)
{
    long long t = (long long)blockIdx.x * blockDim.x + threadIdx.x;
    int node = (int)(t >> 6);
    int lane = threadIdx.x & 63;
    if (node >= NN) return;
    const float* hr = h + (size_t)node * HID;
    float a = hr[lane] * w[lane] + hr[64 + lane] * w[64 + lane];
    #pragma unroll
    for (int off = 32; off > 0; off >>= 1) a += __shfl_down(a, off);
    if (lane == 0) out[node] = a + b[0];
}

extern "C" void kernel_launch(void* const* d_in, const int* in_sizes, int n_in,
                              void* d_out, int out_size, void* d_ws, size_t ws_size,
                              hipStream_t stream)
{
    const float* x     = (const float*)d_in[0];
    const int*   eidx  = (const int*)d_in[1];
    const float* c0_w1 = (const float*)d_in[2],  *c0_b1 = (const float*)d_in[3];
    const float* c0_w2 = (const float*)d_in[4],  *c0_b2 = (const float*)d_in[5];
    const float* c0_w3 = (const float*)d_in[6],  *c0_b3 = (const float*)d_in[7];
    const float* c1_w1 = (const float*)d_in[8],  *c1_b1 = (const float*)d_in[9];
    const float* c1_w2 = (const float*)d_in[10], *c1_b2 = (const float*)d_in[11];
    const float* c1_w3 = (const float*)d_in[12], *c1_b3 = (const float*)d_in[13];
    const float* f_w1  = (const float*)d_in[14], *f_b1  = (const float*)d_in[15];
    const float* f_w2  = (const float*)d_in[16], *f_b2  = (const float*)d_in[17];
    const int* src = eidx;
    const int* dst = eidx + NE;
    float* out = (float*)d_out;

    const size_t BUF = (size_t)NN * HID;           // floats per buffer
    float* b0 = (float*)d_ws;
    float* b1 = b0 + BUF;
    float* b2 = b1 + BUF;
    float* b3 = b2 + BUF;

    const int nb = (NN + 7) / 8;                   // 5000 blocks
    const int sc_blocks = (NE * 32 + 255) / 256;   // 80000 blocks
    const int head_blocks = (NN * 64 + 255) / 256; // 10000 blocks

    // ---- conv0 ----
    lin_kernel<11, true><<<nb, 128, 0, stream>>>(x, c0_w1, c0_b1, b0, NN);
    hipMemsetAsync(b1, 0, BUF * sizeof(float), stream);
    scatter_add_kernel<<<sc_blocks, 256, 0, stream>>>(b0, src, dst, b1);
    lin_kernel<128, true><<<nb, 128, 0, stream>>>(b1, c0_w2, c0_b2, b2, NN);   // l1 = b2
    hipMemsetAsync(b1, 0, BUF * sizeof(float), stream);
    scatter_add_kernel<<<sc_blocks, 256, 0, stream>>>(b2, src, dst, b1);
    lin_kernel<128, true><<<nb, 128, 0, stream>>>(b1, c0_w2, c0_b2, b3, NN);   // l2 = b3
    lin_cat_kernel<false><<<nb, 128, 0, stream>>>(b2, b3, c0_w3, c0_b3, b0, NN); // conv0 out = b0

    // ---- conv1 ----
    lin_kernel<128, true><<<nb, 128, 0, stream>>>(b0, c1_w1, c1_b1, b1, NN);   // h = b1
    hipMemsetAsync(b0, 0, BUF * sizeof(float), stream);
    scatter_add_kernel<<<sc_blocks, 256, 0, stream>>>(b1, src, dst, b0);
    lin_kernel<128, true><<<nb, 128, 0, stream>>>(b0, c1_w2, c1_b2, b2, NN);   // l1 = b2
    hipMemsetAsync(b0, 0, BUF * sizeof(float), stream);
    scatter_add_kernel<<<sc_blocks, 256, 0, stream>>>(b2, src, dst, b0);
    lin_kernel<128, true><<<nb, 128, 0, stream>>>(b0, c1_w2, c1_b2, b3, NN);   // l2 = b3
    lin_cat_kernel<false><<<nb, 128, 0, stream>>>(b2, b3, c1_w3, c1_b3, b1, NN); // conv1 out = b1

    // ---- head ----
    lin_kernel<128, true><<<nb, 128, 0, stream>>>(b1, f_w1, f_b1, b0, NN);
    head_out_kernel<<<head_blocks, 256, 0, stream>>>(b0, f_w2, f_b2, out);
}

// Round 2
// 948.031 us; speedup vs baseline: 5.2380x; 5.2380x over previous
//
#include <hip/hip_runtime.h>

#define NN 40000
#define NE 640000
#define HID 128

// ---------------- Linear layers ----------------
// out[n][m] = (relu?)( sum_k X[n][k] * W[m][k] + b[m] ), W is [HID][K] row-major.
// 128 threads = one per output column m; each block does 8 rows.
// In-place safe (out == X): block stages its 8 rows in LDS before writing.
template<int K, bool RELU>
__global__ __launch_bounds__(128) void lin_kernel(
    const float* __restrict__ X, const float* __restrict__ W,
    const float* __restrict__ b, float* __restrict__ out, int n_rows)
{
    constexpr int ROWS = 8;
    __shared__ float xs[ROWS * K];
    const int m  = threadIdx.x;
    const int r0 = blockIdx.x * ROWS;
    for (int i = threadIdx.x; i < ROWS * K; i += 128) {
        int r = i / K, k = i - r * K;
        int row = r0 + r;
        xs[i] = (row < n_rows) ? X[(size_t)row * K + k] : 0.f;
    }
    __syncthreads();
    float acc[ROWS] = {};
    const float* Wm = W + (size_t)m * K;
    for (int k = 0; k < K; ++k) {
        float w = Wm[k];
        #pragma unroll
        for (int r = 0; r < ROWS; ++r) acc[r] += xs[r * K + k] * w;
    }
    const float bias = b[m];
    #pragma unroll
    for (int r = 0; r < ROWS; ++r) {
        int row = r0 + r;
        if (row < n_rows) {
            float v = acc[r] + bias;
            out[(size_t)row * HID + m] = RELU ? fmaxf(v, 0.f) : v;
        }
    }
}

// Concat variant: X = [A | B] per row, K = 256, W is [HID][256].
template<bool RELU>
__global__ __launch_bounds__(128) void lin_cat_kernel(
    const float* __restrict__ A, const float* __restrict__ B,
    const float* __restrict__ W, const float* __restrict__ b,
    float* __restrict__ out, int n_rows)
{
    constexpr int ROWS = 8;
    constexpr int K = 2 * HID;
    __shared__ float xs[ROWS * K];
    const int m  = threadIdx.x;
    const int r0 = blockIdx.x * ROWS;
    for (int i = threadIdx.x; i < ROWS * HID; i += 128) {
        int r = i / HID, k = i - r * HID;
        int row = r0 + r;
        float a = 0.f, bb = 0.f;
        if (row < n_rows) {
            a  = A[(size_t)row * HID + k];
            bb = B[(size_t)row * HID + k];
        }
        xs[r * K + k]       = a;
        xs[r * K + HID + k] = bb;
    }
    __syncthreads();
    float acc[ROWS] = {};
    const float* Wm = W + (size_t)m * K;
    for (int k = 0; k < K; ++k) {
        float w = Wm[k];
        #pragma unroll
        for (int r = 0; r < ROWS; ++r) acc[r] += xs[r * K + k] * w;
    }
    const float bias = b[m];
    #pragma unroll
    for (int r = 0; r < ROWS; ++r) {
        int row = r0 + r;
        if (row < n_rows) {
            float v = acc[r] + bias;
            out[(size_t)row * HID + m] = RELU ? fmaxf(v, 0.f) : v;
        }
    }
}

// ---------------- CSR build (by dst) ----------------
__global__ __launch_bounds__(256) void hist_kernel(
    const int* __restrict__ dst, int* __restrict__ cnt)
{
    int e = blockIdx.x * 256 + threadIdx.x;
    if (e < NE) atomicAdd(&cnt[dst[e]], 1);
}

// Single-block exclusive scan of cnt[0..NN) -> row_ptr[0..NN], 1024 threads.
__global__ __launch_bounds__(1024) void scan_kernel(
    const int* __restrict__ cnt, int* __restrict__ row_ptr)
{
    __shared__ int sums[1024];
    const int T = 1024;
    const int t = threadIdx.x;
    const int per = (NN + T - 1) / T;   // 40
    const int lo = t * per;
    const int hi = (lo + per < NN) ? lo + per : NN;
    int s = 0;
    for (int i = lo; i < hi; ++i) s += cnt[i];
    sums[t] = s;
    __syncthreads();
    for (int off = 1; off < T; off <<= 1) {
        int v = 0;
        if (t >= off) v = sums[t - off];
        __syncthreads();
        if (t >= off) sums[t] += v;
        __syncthreads();
    }
    int base = (t == 0) ? 0 : sums[t - 1];
    for (int i = lo; i < hi; ++i) {
        row_ptr[i] = base;
        base += cnt[i];
    }
    if (t == T - 1) row_ptr[NN] = base;  // == NE
}

__global__ __launch_bounds__(256) void fill_kernel(
    const int* __restrict__ src, const int* __restrict__ dst,
    const int* __restrict__ row_ptr, int* __restrict__ pos,
    int* __restrict__ esrc)
{
    int e = blockIdx.x * 256 + threadIdx.x;
    if (e >= NE) return;
    int d = dst[e];
    int p = row_ptr[d] + atomicAdd(&pos[d], 1);
    esrc[p] = src[e];
}

// ---------------- Gather aggregation (atomic-free) ----------------
// agg[n][:] = sum over incoming edges e of h[esrc[e]][:].
// 32 lanes per node, float4 per lane. 256-thread block = 8 nodes.
__global__ __launch_bounds__(256) void gather_agg_kernel(
    const float* __restrict__ h, const int* __restrict__ row_ptr,
    const int* __restrict__ esrc, float* __restrict__ agg)
{
    int t = blockIdx.x * 256 + threadIdx.x;
    int node = t >> 5;
    int c4   = t & 31;
    if (node >= NN) return;
    const int lo = row_ptr[node], hi = row_ptr[node + 1];
    float4 acc = make_float4(0.f, 0.f, 0.f, 0.f);
    for (int e = lo; e < hi; ++e) {
        int s = esrc[e];  // broadcast across the 32 lanes
        float4 v = *(const float4*)(h + (size_t)s * HID + c4 * 4);
        acc.x += v.x; acc.y += v.y; acc.z += v.z; acc.w += v.w;
    }
    *(float4*)(agg + (size_t)node * HID + c4 * 4) = acc;
}

// ---------------- Head ----------------
__global__ __launch_bounds__(256) void head_out_kernel(
    const float* __restrict__ h, const float* __restrict__ w,
    const float* __restrict__ b, float* __restrict__ out)
{
    long long t = (long long)blockIdx.x * blockDim.x + threadIdx.x;
    int node = (int)(t >> 6);
    int lane = threadIdx.x & 63;
    if (node >= NN) return;
    const float* hr = h + (size_t)node * HID;
    float a = hr[lane] * w[lane] + hr[64 + lane] * w[64 + lane];
    #pragma unroll
    for (int off = 32; off > 0; off >>= 1) a += __shfl_down(a, off);
    if (lane == 0) out[node] = a + b[0];
}

extern "C" void kernel_launch(void* const* d_in, const int* in_sizes, int n_in,
                              void* d_out, int out_size, void* d_ws, size_t ws_size,
                              hipStream_t stream)
{
    const float* x     = (const float*)d_in[0];
    const int*   eidx  = (const int*)d_in[1];
    const float* c0_w1 = (const float*)d_in[2],  *c0_b1 = (const float*)d_in[3];
    const float* c0_w2 = (const float*)d_in[4],  *c0_b2 = (const float*)d_in[5];
    const float* c0_w3 = (const float*)d_in[6],  *c0_b3 = (const float*)d_in[7];
    const float* c1_w1 = (const float*)d_in[8],  *c1_b1 = (const float*)d_in[9];
    const float* c1_w2 = (const float*)d_in[10], *c1_b2 = (const float*)d_in[11];
    const float* c1_w3 = (const float*)d_in[12], *c1_b3 = (const float*)d_in[13];
    const float* f_w1  = (const float*)d_in[14], *f_b1  = (const float*)d_in[15];
    const float* f_w2  = (const float*)d_in[16], *f_b2  = (const float*)d_in[17];
    const int* src = eidx;
    const int* dst = eidx + NE;
    float* out = (float*)d_out;

    // Workspace layout: 3 float buffers + CSR ints (~64.3 MB total)
    const size_t BUF = (size_t)NN * HID;
    float* bA = (float*)d_ws;
    float* bB = bA + BUF;
    float* bC = bB + BUF;
    int* row_ptr = (int*)(bC + BUF);      // NN+1
    int* cnt     = row_ptr + (NN + 1);    // NN (reused as fill cursor)
    int* esrc    = cnt + NN;              // NE

    const int nb = (NN + 7) / 8;                     // 5000
    const int eb = (NE + 255) / 256;                 // 2500
    const int gb = (NN * 32 + 255) / 256;            // 5000
    const int hb = (NN * 64 + 255) / 256;            // 10000

    // ---- CSR build (same work every call; edge_index restored each call) ----
    hipMemsetAsync(cnt, 0, NN * sizeof(int), stream);
    hist_kernel<<<eb, 256, 0, stream>>>(dst, cnt);
    scan_kernel<<<1, 1024, 0, stream>>>(cnt, row_ptr);
    hipMemsetAsync(cnt, 0, NN * sizeof(int), stream);
    fill_kernel<<<eb, 256, 0, stream>>>(src, dst, row_ptr, cnt, esrc);

    // ---- conv0 ----
    lin_kernel<11, true><<<nb, 128, 0, stream>>>(x, c0_w1, c0_b1, bA, NN);
    gather_agg_kernel<<<gb, 256, 0, stream>>>(bA, row_ptr, esrc, bB);
    lin_kernel<128, true><<<nb, 128, 0, stream>>>(bB, c0_w2, c0_b2, bB, NN);   // l1 = bB
    gather_agg_kernel<<<gb, 256, 0, stream>>>(bB, row_ptr, esrc, bC);
    lin_kernel<128, true><<<nb, 128, 0, stream>>>(bC, c0_w2, c0_b2, bC, NN);   // l2 = bC
    lin_cat_kernel<false><<<nb, 128, 0, stream>>>(bB, bC, c0_w3, c0_b3, bA, NN); // conv0 out = bA

    // ---- conv1 ----
    lin_kernel<128, true><<<nb, 128, 0, stream>>>(bA, c1_w1, c1_b1, bA, NN);   // h = bA
    gather_agg_kernel<<<gb, 256, 0, stream>>>(bA, row_ptr, esrc, bB);
    lin_kernel<128, true><<<nb, 128, 0, stream>>>(bB, c1_w2, c1_b2, bB, NN);   // l1 = bB
    gather_agg_kernel<<<gb, 256, 0, stream>>>(bB, row_ptr, esrc, bC);
    lin_kernel<128, true><<<nb, 128, 0, stream>>>(bC, c1_w2, c1_b2, bC, NN);   // l2 = bC
    lin_cat_kernel<false><<<nb, 128, 0, stream>>>(bB, bC, c1_w3, c1_b3, bA, NN); // conv1 out = bA

    // ---- head ----
    lin_kernel<128, true><<<nb, 128, 0, stream>>>(bA, f_w1, f_b1, bA, NN);
    head_out_kernel<<<hb, 256, 0, stream>>>(bA, f_w2, f_b2, out);
}

// Round 5
// 632.213 us; speedup vs baseline: 7.8546x; 1.4995x over previous
//
#include <hip/hip_runtime.h>

#define NN 40000
#define NE 640000
#define HID 128

typedef __attribute__((ext_vector_type(8)))  short short8;
typedef __attribute__((ext_vector_type(4)))  short short4v;
typedef __attribute__((ext_vector_type(16))) float floatx16;

__device__ __forceinline__ short f2bf(float f) {
    union { float f; unsigned u; } c; c.f = f;
    unsigned u = c.u;
    unsigned r = (u + 0x7FFF + ((u >> 16) & 1)) >> 16;   // RNE
    return (short)r;
}
__device__ __forceinline__ float bf2f(short h) {
    union { unsigned u; float f; } c;
    c.u = ((unsigned)(unsigned short)h) << 16;
    return c.f;
}
// x ~= hi + lo, both bf16; combined ~2^-17 relative error.
__device__ __forceinline__ void splitbf(float f, short* hi, short* lo) {
    short h = f2bf(f);
    *hi = h;
    *lo = f2bf(f - bf2f(h));
}
__device__ __forceinline__ void split4(float4 f, short4v* hi, short4v* lo) {
    short hx, lx, hy, ly, hz, lz, hw, lw;
    splitbf(f.x, &hx, &lx); splitbf(f.y, &hy, &ly);
    splitbf(f.z, &hz, &lz); splitbf(f.w, &hw, &lw);
    short4v h, l;
    h.x = hx; h.y = hy; h.z = hz; h.w = hw;
    l.x = lx; l.y = ly; l.z = lz; l.w = lw;
    *hi = h; *lo = l;
}

// ---------------- split-bf16 MFMA linear ----------------
// out[N][128] = relu?( X · W^T + b ). X supplied as PHASES blocks of 128 fp32
// columns (X0, X1), row stride 128; W is [128][PHASES*128] row-major fp32.
// Split-bf16: acc += xh*wh + xl*wh + xh*wl (fp32 accum) -> fp32-grade result.
// Block: 256 thr = 4 waves; tile 128 rows x 128 cols; BK=64 per k-stage.
// In-place safe (out==X0): all X reads precede the epilogue store.
template<int PHASES, bool RELU>
__global__ __launch_bounds__(256, 2) void mfma_lin_kernel(
    const float* __restrict__ X0, const float* __restrict__ X1,
    const float* __restrict__ W, const float* __restrict__ b,
    float* __restrict__ out)
{
    constexpr int LDK = 72;                  // 64 + 8 shorts (16B pad)
    __shared__ short sAh[128 * LDK];
    __shared__ short sAl[128 * LDK];
    __shared__ short sWh[128 * LDK];
    __shared__ short sWl[128 * LDK];

    const int t    = threadIdx.x;
    const int wave = t >> 6;
    const int lane = t & 63;
    const int r0   = blockIdx.x * 128;
    const int WS   = PHASES * 128;           // W row stride

    floatx16 acc[4];
    #pragma unroll
    for (int ct = 0; ct < 4; ++ct)
        #pragma unroll
        for (int i = 0; i < 16; ++i) acc[ct][i] = 0.f;

    const int m31  = lane & 31;
    const int half = lane >> 5;              // k-subchunk within K16
    const int aOff = (wave * 32 + m31) * LDK + half * 8;
    const int wOff = m31 * LDK + half * 8;

    for (int s = 0; s < 2 * PHASES; ++s) {   // k-stages of 64
        const int p     = s >> 1;
        const int xc0   = (s & 1) * 64;      // col offset within X row
        const int wc0   = p * 128 + xc0;     // col offset within W row
        const float* Xp = (PHASES == 2 && p == 1) ? X1 : X0;

        // stage X tile: 128 rows x 64 cols -> sAh/sAl (2048 float4s, 8/thread)
        #pragma unroll
        for (int i = 0; i < 8; ++i) {
            int v   = t + 256 * i;
            int row = v >> 4;
            int c4  = (v & 15) * 4;
            int gr  = r0 + row;
            float4 f = make_float4(0.f, 0.f, 0.f, 0.f);
            if (gr < NN) f = *(const float4*)(Xp + (size_t)gr * 128 + xc0 + c4);
            short4v hi, lo;
            split4(f, &hi, &lo);
            *(short4v*)(sAh + row * LDK + c4) = hi;
            *(short4v*)(sAl + row * LDK + c4) = lo;
        }
        // stage W tile: 128 out-cols x 64 k-cols -> sWh/sWl
        #pragma unroll
        for (int i = 0; i < 8; ++i) {
            int v   = t + 256 * i;
            int row = v >> 4;
            int c4  = (v & 15) * 4;
            float4 f = *(const float4*)(W + (size_t)row * WS + wc0 + c4);
            short4v hi, lo;
            split4(f, &hi, &lo);
            *(short4v*)(sWh + row * LDK + c4) = hi;
            *(short4v*)(sWl + row * LDK + c4) = lo;
        }
        __syncthreads();

        #pragma unroll
        for (int kc = 0; kc < 4; ++kc) {     // 4 x K16
            short8 ah = *(const short8*)(sAh + aOff + kc * 16);
            short8 al = *(const short8*)(sAl + aOff + kc * 16);
            #pragma unroll
            for (int ct = 0; ct < 4; ++ct) {
                short8 bh = *(const short8*)(sWh + wOff + ct * 32 * LDK + kc * 16);
                short8 bl = *(const short8*)(sWl + wOff + ct * 32 * LDK + kc * 16);
                acc[ct] = __builtin_amdgcn_mfma_f32_32x32x16_bf16(ah, bh, acc[ct], 0, 0, 0);
                acc[ct] = __builtin_amdgcn_mfma_f32_32x32x16_bf16(al, bh, acc[ct], 0, 0, 0);
                acc[ct] = __builtin_amdgcn_mfma_f32_32x32x16_bf16(ah, bl, acc[ct], 0, 0, 0);
            }
        }
        __syncthreads();                     // guard LDS restage
    }

    // epilogue: bias + relu + store. C/D: col=lane&31, row=(reg&3)+8*(reg>>2)+4*half
    #pragma unroll
    for (int ct = 0; ct < 4; ++ct) {
        int col = ct * 32 + m31;
        float bias = b[col];
        #pragma unroll
        for (int reg = 0; reg < 16; ++reg) {
            int row = (reg & 3) + 8 * (reg >> 2) + 4 * half;
            int gr  = r0 + wave * 32 + row;
            if (gr < NN) {
                float v = acc[ct][reg] + bias;
                out[(size_t)gr * HID + col] = RELU ? fmaxf(v, 0.f) : v;
            }
        }
    }
}

// ---------------- fp32 linear for K=11 (first embed only) ----------------
template<int K, bool RELU>
__global__ __launch_bounds__(128) void lin_kernel(
    const float* __restrict__ X, const float* __restrict__ W,
    const float* __restrict__ b, float* __restrict__ out, int n_rows)
{
    constexpr int ROWS = 8;
    __shared__ float xs[ROWS * K];
    const int m  = threadIdx.x;
    const int r0 = blockIdx.x * ROWS;
    for (int i = threadIdx.x; i < ROWS * K; i += 128) {
        int r = i / K, k = i - r * K;
        int row = r0 + r;
        xs[i] = (row < n_rows) ? X[(size_t)row * K + k] : 0.f;
    }
    __syncthreads();
    float acc[ROWS] = {};
    const float* Wm = W + (size_t)m * K;
    for (int k = 0; k < K; ++k) {
        float w = Wm[k];
        #pragma unroll
        for (int r = 0; r < ROWS; ++r) acc[r] += xs[r * K + k] * w;
    }
    const float bias = b[m];
    #pragma unroll
    for (int r = 0; r < ROWS; ++r) {
        int row = r0 + r;
        if (row < n_rows) {
            float v = acc[r] + bias;
            out[(size_t)row * HID + m] = RELU ? fmaxf(v, 0.f) : v;
        }
    }
}

// ---------------- CSR build (by dst) ----------------
__global__ __launch_bounds__(256) void hist_kernel(
    const int* __restrict__ dst, int* __restrict__ cnt)
{
    int e = blockIdx.x * 256 + threadIdx.x;
    if (e < NE) atomicAdd(&cnt[dst[e]], 1);
}

__global__ __launch_bounds__(1024) void scan_kernel(
    const int* __restrict__ cnt, int* __restrict__ row_ptr)
{
    __shared__ int sums[1024];
    const int T = 1024;
    const int t = threadIdx.x;
    const int per = (NN + T - 1) / T;
    const int lo = t * per;
    const int hi = (lo + per < NN) ? lo + per : NN;
    int s = 0;
    for (int i = lo; i < hi; ++i) s += cnt[i];
    sums[t] = s;
    __syncthreads();
    for (int off = 1; off < T; off <<= 1) {
        int v = 0;
        if (t >= off) v = sums[t - off];
        __syncthreads();
        if (t >= off) sums[t] += v;
        __syncthreads();
    }
    int base = (t == 0) ? 0 : sums[t - 1];
    for (int i = lo; i < hi; ++i) {
        row_ptr[i] = base;
        base += cnt[i];
    }
    if (t == T - 1) row_ptr[NN] = base;
}

__global__ __launch_bounds__(256) void fill_kernel(
    const int* __restrict__ src, const int* __restrict__ dst,
    const int* __restrict__ row_ptr, int* __restrict__ pos,
    int* __restrict__ esrc)
{
    int e = blockIdx.x * 256 + threadIdx.x;
    if (e >= NE) return;
    int d = dst[e];
    int p = row_ptr[d] + atomicAdd(&pos[d], 1);
    esrc[p] = src[e];
}

// ---------------- Gather aggregation (atomic-free) ----------------
__global__ __launch_bounds__(256) void gather_agg_kernel(
    const float* __restrict__ h, const int* __restrict__ row_ptr,
    const int* __restrict__ esrc, float* __restrict__ agg)
{
    int t = blockIdx.x * 256 + threadIdx.x;
    int node = t >> 5;
    int c4   = t & 31;
    if (node >= NN) return;
    const int lo = row_ptr[node], hi = row_ptr[node + 1];
    float4 acc = make_float4(0.f, 0.f, 0.f, 0.f);
    for (int e = lo; e < hi; ++e) {
        int s = esrc[e];
        float4 v = *(const float4*)(h + (size_t)s * HID + c4 * 4);
        acc.x += v.x; acc.y += v.y; acc.z += v.z; acc.w += v.w;
    }
    *(float4*)(agg + (size_t)node * HID + c4 * 4) = acc;
}

// ---------------- Head ----------------
__global__ __launch_bounds__(256) void head_out_kernel(
    const float* __restrict__ h, const float* __restrict__ w,
    const float* __restrict__ b, float* __restrict__ out)
{
    long long t = (long long)blockIdx.x * blockDim.x + threadIdx.x;
    int node = (int)(t >> 6);
    int lane = threadIdx.x & 63;
    if (node >= NN) return;
    const float* hr = h + (size_t)node * HID;
    float a = hr[lane] * w[lane] + hr[64 + lane] * w[64 + lane];
    #pragma unroll
    for (int off = 32; off > 0; off >>= 1) a += __shfl_down(a, off);
    if (lane == 0) out[node] = a + b[0];
}

extern "C" void kernel_launch(void* const* d_in, const int* in_sizes, int n_in,
                              void* d_out, int out_size, void* d_ws, size_t ws_size,
                              hipStream_t stream)
{
    const float* x     = (const float*)d_in[0];
    const int*   eidx  = (const int*)d_in[1];
    const float* c0_w1 = (const float*)d_in[2],  *c0_b1 = (const float*)d_in[3];
    const float* c0_w2 = (const float*)d_in[4],  *c0_b2 = (const float*)d_in[5];
    const float* c0_w3 = (const float*)d_in[6],  *c0_b3 = (const float*)d_in[7];
    const float* c1_w1 = (const float*)d_in[8],  *c1_b1 = (const float*)d_in[9];
    const float* c1_w2 = (const float*)d_in[10], *c1_b2 = (const float*)d_in[11];
    const float* c1_w3 = (const float*)d_in[12], *c1_b3 = (const float*)d_in[13];
    const float* f_w1  = (const float*)d_in[14], *f_b1  = (const float*)d_in[15];
    const float* f_w2  = (const float*)d_in[16], *f_b2  = (const float*)d_in[17];
    const int* src = eidx;
    const int* dst = eidx + NE;
    float* out = (float*)d_out;

    const size_t BUF = (size_t)NN * HID;
    float* bA = (float*)d_ws;
    float* bB = bA + BUF;
    float* bC = bB + BUF;
    int* row_ptr = (int*)(bC + BUF);
    int* cnt     = row_ptr + (NN + 1);
    int* esrc    = cnt + NN;

    const int nb8  = (NN + 7) / 8;            // 5000 (K=11 lin)
    const int nbm  = (NN + 127) / 128;        // 313 (mfma lin)
    const int eb   = (NE + 255) / 256;        // 2500
    const int gb   = (NN * 32 + 255) / 256;   // 5000
    const int hb   = (NN * 64 + 255) / 256;   // 10000

    // ---- CSR build ----
    (void)hipMemsetAsync(cnt, 0, NN * sizeof(int), stream);
    hist_kernel<<<eb, 256, 0, stream>>>(dst, cnt);
    scan_kernel<<<1, 1024, 0, stream>>>(cnt, row_ptr);
    (void)hipMemsetAsync(cnt, 0, NN * sizeof(int), stream);
    fill_kernel<<<eb, 256, 0, stream>>>(src, dst, row_ptr, cnt, esrc);

    // ---- conv0 ----
    lin_kernel<11, true><<<nb8, 128, 0, stream>>>(x, c0_w1, c0_b1, bA, NN);
    gather_agg_kernel<<<gb, 256, 0, stream>>>(bA, row_ptr, esrc, bB);
    mfma_lin_kernel<1, true><<<nbm, 256, 0, stream>>>(bB, nullptr, c0_w2, c0_b2, bB);   // l1 = bB
    gather_agg_kernel<<<gb, 256, 0, stream>>>(bB, row_ptr, esrc, bC);
    mfma_lin_kernel<1, true><<<nbm, 256, 0, stream>>>(bC, nullptr, c0_w2, c0_b2, bC);   // l2 = bC
    mfma_lin_kernel<2, false><<<nbm, 256, 0, stream>>>(bB, bC, c0_w3, c0_b3, bA);       // conv0 out = bA

    // ---- conv1 ----
    mfma_lin_kernel<1, true><<<nbm, 256, 0, stream>>>(bA, nullptr, c1_w1, c1_b1, bA);   // h = bA
    gather_agg_kernel<<<gb, 256, 0, stream>>>(bA, row_ptr, esrc, bB);
    mfma_lin_kernel<1, true><<<nbm, 256, 0, stream>>>(bB, nullptr, c1_w2, c1_b2, bB);   // l1 = bB
    gather_agg_kernel<<<gb, 256, 0, stream>>>(bB, row_ptr, esrc, bC);
    mfma_lin_kernel<1, true><<<nbm, 256, 0, stream>>>(bC, nullptr, c1_w2, c1_b2, bC);   // l2 = bC
    mfma_lin_kernel<2, false><<<nbm, 256, 0, stream>>>(bB, bC, c1_w3, c1_b3, bA);       // conv1 out = bA

    // ---- head ----
    mfma_lin_kernel<1, true><<<nbm, 256, 0, stream>>>(bA, nullptr, f_w1, f_b1, bA);
    head_out_kernel<<<hb, 256, 0, stream>>>(bA, f_w2, f_b2, out);
}

// Round 6
// 578.496 us; speedup vs baseline: 8.5839x; 1.0929x over previous
//
#include <hip/hip_runtime.h>

#define NN 40000
#define NE 640000
#define HID 128
#define SCAN_BLK ((NN + 255) / 256)   // 157

typedef __attribute__((ext_vector_type(8)))  short short8;
typedef __attribute__((ext_vector_type(4)))  short short4v;
typedef __attribute__((ext_vector_type(16))) float floatx16;

__device__ __forceinline__ short f2bf(float f) {
    union { float f; unsigned u; } c; c.f = f;
    unsigned u = c.u;
    unsigned r = (u + 0x7FFF + ((u >> 16) & 1)) >> 16;   // RNE
    return (short)r;
}
__device__ __forceinline__ float bf2f(short h) {
    union { unsigned u; float f; } c;
    c.u = ((unsigned)(unsigned short)h) << 16;
    return c.f;
}
// x ~= hi + lo, both bf16; combined ~2^-17 relative error.
__device__ __forceinline__ void splitbf(float f, short* hi, short* lo) {
    short h = f2bf(f);
    *hi = h;
    *lo = f2bf(f - bf2f(h));
}
__device__ __forceinline__ void split4(float4 f, short4v* hi, short4v* lo) {
    short hx, lx, hy, ly, hz, lz, hw, lw;
    splitbf(f.x, &hx, &lx); splitbf(f.y, &hy, &ly);
    splitbf(f.z, &hz, &lz); splitbf(f.w, &hw, &lw);
    short4v h, l;
    h.x = hx; h.y = hy; h.z = hz; h.w = hw;
    l.x = lx; l.y = ly; l.z = lz; l.w = lw;
    *hi = h; *lo = l;
}

// ---------------- split-bf16 MFMA linear ----------------
// out[N][128] = relu?( X · W^T + b ). X supplied as PHASES blocks of 128 fp32
// columns (X0, X1), row stride 128; W is [128][PHASES*128] row-major fp32.
// Split-bf16: acc += xh*wh + xl*wh + xh*wl (fp32 accum) -> fp32-grade result.
// Block: 256 thr = 4 waves; tile 128 rows x 128 cols; BK=64 per k-stage.
// In-place safe (out==X0): all X reads precede the epilogue store.
template<int PHASES, bool RELU>
__global__ __launch_bounds__(256, 2) void mfma_lin_kernel(
    const float* __restrict__ X0, const float* __restrict__ X1,
    const float* __restrict__ W, const float* __restrict__ b,
    float* __restrict__ out)
{
    constexpr int LDK = 72;                  // 64 + 8 shorts (16B pad)
    __shared__ short sAh[128 * LDK];
    __shared__ short sAl[128 * LDK];
    __shared__ short sWh[128 * LDK];
    __shared__ short sWl[128 * LDK];

    const int t    = threadIdx.x;
    const int wave = t >> 6;
    const int lane = t & 63;
    const int r0   = blockIdx.x * 128;
    const int WS   = PHASES * 128;           // W row stride

    floatx16 acc[4];
    #pragma unroll
    for (int ct = 0; ct < 4; ++ct)
        #pragma unroll
        for (int i = 0; i < 16; ++i) acc[ct][i] = 0.f;

    const int m31  = lane & 31;
    const int half = lane >> 5;              // k-subchunk within K16
    const int aOff = (wave * 32 + m31) * LDK + half * 8;
    const int wOff = m31 * LDK + half * 8;

    for (int s = 0; s < 2 * PHASES; ++s) {   // k-stages of 64
        const int p     = s >> 1;
        const int xc0   = (s & 1) * 64;      // col offset within X row
        const int wc0   = p * 128 + xc0;     // col offset within W row
        const float* Xp = (PHASES == 2 && p == 1) ? X1 : X0;

        // stage X tile: 128 rows x 64 cols -> sAh/sAl (2048 float4s, 8/thread)
        #pragma unroll
        for (int i = 0; i < 8; ++i) {
            int v   = t + 256 * i;
            int row = v >> 4;
            int c4  = (v & 15) * 4;
            int gr  = r0 + row;
            float4 f = make_float4(0.f, 0.f, 0.f, 0.f);
            if (gr < NN) f = *(const float4*)(Xp + (size_t)gr * 128 + xc0 + c4);
            short4v hi, lo;
            split4(f, &hi, &lo);
            *(short4v*)(sAh + row * LDK + c4) = hi;
            *(short4v*)(sAl + row * LDK + c4) = lo;
        }
        // stage W tile: 128 out-cols x 64 k-cols -> sWh/sWl
        #pragma unroll
        for (int i = 0; i < 8; ++i) {
            int v   = t + 256 * i;
            int row = v >> 4;
            int c4  = (v & 15) * 4;
            float4 f = *(const float4*)(W + (size_t)row * WS + wc0 + c4);
            short4v hi, lo;
            split4(f, &hi, &lo);
            *(short4v*)(sWh + row * LDK + c4) = hi;
            *(short4v*)(sWl + row * LDK + c4) = lo;
        }
        __syncthreads();

        #pragma unroll
        for (int kc = 0; kc < 4; ++kc) {     // 4 x K16
            short8 ah = *(const short8*)(sAh + aOff + kc * 16);
            short8 al = *(const short8*)(sAl + aOff + kc * 16);
            #pragma unroll
            for (int ct = 0; ct < 4; ++ct) {
                short8 bh = *(const short8*)(sWh + wOff + ct * 32 * LDK + kc * 16);
                short8 bl = *(const short8*)(sWl + wOff + ct * 32 * LDK + kc * 16);
                acc[ct] = __builtin_amdgcn_mfma_f32_32x32x16_bf16(ah, bh, acc[ct], 0, 0, 0);
                acc[ct] = __builtin_amdgcn_mfma_f32_32x32x16_bf16(al, bh, acc[ct], 0, 0, 0);
                acc[ct] = __builtin_amdgcn_mfma_f32_32x32x16_bf16(ah, bl, acc[ct], 0, 0, 0);
            }
        }
        __syncthreads();                     // guard LDS restage
    }

    // epilogue: bias + relu + store. C/D: col=lane&31, row=(reg&3)+8*(reg>>2)+4*half
    #pragma unroll
    for (int ct = 0; ct < 4; ++ct) {
        int col = ct * 32 + m31;
        float bias = b[col];
        #pragma unroll
        for (int reg = 0; reg < 16; ++reg) {
            int row = (reg & 3) + 8 * (reg >> 2) + 4 * half;
            int gr  = r0 + wave * 32 + row;
            if (gr < NN) {
                float v = acc[ct][reg] + bias;
                out[(size_t)gr * HID + col] = RELU ? fmaxf(v, 0.f) : v;
            }
        }
    }
}

// ---------------- fp32 linear for K=11 (first embed only) ----------------
template<int K, bool RELU>
__global__ __launch_bounds__(128) void lin_kernel(
    const float* __restrict__ X, const float* __restrict__ W,
    const float* __restrict__ b, float* __restrict__ out, int n_rows)
{
    constexpr int ROWS = 8;
    __shared__ float xs[ROWS * K];
    const int m  = threadIdx.x;
    const int r0 = blockIdx.x * ROWS;
    for (int i = threadIdx.x; i < ROWS * K; i += 128) {
        int r = i / K, k = i - r * K;
        int row = r0 + r;
        xs[i] = (row < n_rows) ? X[(size_t)row * K + k] : 0.f;
    }
    __syncthreads();
    float acc[ROWS] = {};
    const float* Wm = W + (size_t)m * K;
    for (int k = 0; k < K; ++k) {
        float w = Wm[k];
        #pragma unroll
        for (int r = 0; r < ROWS; ++r) acc[r] += xs[r * K + k] * w;
    }
    const float bias = b[m];
    #pragma unroll
    for (int r = 0; r < ROWS; ++r) {
        int row = r0 + r;
        if (row < n_rows) {
            float v = acc[r] + bias;
            out[(size_t)row * HID + m] = RELU ? fmaxf(v, 0.f) : v;
        }
    }
}

// ---------------- CSR build (by dst) ----------------
__global__ __launch_bounds__(256) void hist_kernel(
    const int* __restrict__ dst, int* __restrict__ cnt)
{
    int e = blockIdx.x * 256 + threadIdx.x;
    if (e < NE) atomicAdd(&cnt[dst[e]], 1);
}

// Hierarchical scan, phase 1: per-block (256-wide) exclusive scan of cnt,
// local prefixes -> row_ptr, block total -> partials[blockIdx].
__global__ __launch_bounds__(256) void scan1_kernel(
    const int* __restrict__ cnt, int* __restrict__ row_ptr,
    int* __restrict__ partials)
{
    __shared__ int s[256];
    const int t = threadIdx.x;
    const int i = blockIdx.x * 256 + t;
    int v = (i < NN) ? cnt[i] : 0;
    s[t] = v;
    __syncthreads();
    #pragma unroll
    for (int off = 1; off < 256; off <<= 1) {
        int x = (t >= off) ? s[t - off] : 0;
        __syncthreads();
        s[t] += x;
        __syncthreads();
    }
    if (i < NN) row_ptr[i] = s[t] - v;       // exclusive local prefix
    if (t == 255) partials[blockIdx.x] = s[255];
}

// Phase 2: single block exclusive-scans partials[SCAN_BLK]; writes row_ptr[NN].
__global__ __launch_bounds__(256) void scan2_kernel(
    int* __restrict__ partials, int* __restrict__ row_ptr)
{
    __shared__ int s[256];
    const int t = threadIdx.x;
    int v = (t < SCAN_BLK) ? partials[t] : 0;
    s[t] = v;
    __syncthreads();
    #pragma unroll
    for (int off = 1; off < 256; off <<= 1) {
        int x = (t >= off) ? s[t - off] : 0;
        __syncthreads();
        s[t] += x;
        __syncthreads();
    }
    if (t < SCAN_BLK) partials[t] = s[t] - v;  // exclusive block offsets
    if (t == 255) row_ptr[NN] = s[255];        // == NE
}

// Phase 3: add block offsets.
__global__ __launch_bounds__(256) void scan3_kernel(
    int* __restrict__ row_ptr, const int* __restrict__ partials)
{
    const int i = blockIdx.x * 256 + threadIdx.x;
    if (i < NN) row_ptr[i] += partials[blockIdx.x];
}

__global__ __launch_bounds__(256) void fill_kernel(
    const int* __restrict__ src, const int* __restrict__ dst,
    const int* __restrict__ row_ptr, int* __restrict__ pos,
    int* __restrict__ esrc)
{
    int e = blockIdx.x * 256 + threadIdx.x;
    if (e >= NE) return;
    int d = dst[e];
    int p = row_ptr[d] + atomicAdd(&pos[d], 1);
    esrc[p] = src[e];
}

// ---------------- Gather aggregation (atomic-free) ----------------
__global__ __launch_bounds__(256) void gather_agg_kernel(
    const float* __restrict__ h, const int* __restrict__ row_ptr,
    const int* __restrict__ esrc, float* __restrict__ agg)
{
    int t = blockIdx.x * 256 + threadIdx.x;
    int node = t >> 5;
    int c4   = t & 31;
    if (node >= NN) return;
    const int lo = row_ptr[node], hi = row_ptr[node + 1];
    float4 acc = make_float4(0.f, 0.f, 0.f, 0.f);
    for (int e = lo; e < hi; ++e) {
        int s = esrc[e];
        float4 v = *(const float4*)(h + (size_t)s * HID + c4 * 4);
        acc.x += v.x; acc.y += v.y; acc.z += v.z; acc.w += v.w;
    }
    *(float4*)(agg + (size_t)node * HID + c4 * 4) = acc;
}

// ---------------- Head ----------------
__global__ __launch_bounds__(256) void head_out_kernel(
    const float* __restrict__ h, const float* __restrict__ w,
    const float* __restrict__ b, float* __restrict__ out)
{
    long long t = (long long)blockIdx.x * blockDim.x + threadIdx.x;
    int node = (int)(t >> 6);
    int lane = threadIdx.x & 63;
    if (node >= NN) return;
    const float* hr = h + (size_t)node * HID;
    float a = hr[lane] * w[lane] + hr[64 + lane] * w[64 + lane];
    #pragma unroll
    for (int off = 32; off > 0; off >>= 1) a += __shfl_down(a, off);
    if (lane == 0) out[node] = a + b[0];
}

extern "C" void kernel_launch(void* const* d_in, const int* in_sizes, int n_in,
                              void* d_out, int out_size, void* d_ws, size_t ws_size,
                              hipStream_t stream)
{
    const float* x     = (const float*)d_in[0];
    const int*   eidx  = (const int*)d_in[1];
    const float* c0_w1 = (const float*)d_in[2],  *c0_b1 = (const float*)d_in[3];
    const float* c0_w2 = (const float*)d_in[4],  *c0_b2 = (const float*)d_in[5];
    const float* c0_w3 = (const float*)d_in[6],  *c0_b3 = (const float*)d_in[7];
    const float* c1_w1 = (const float*)d_in[8],  *c1_b1 = (const float*)d_in[9];
    const float* c1_w2 = (const float*)d_in[10], *c1_b2 = (const float*)d_in[11];
    const float* c1_w3 = (const float*)d_in[12], *c1_b3 = (const float*)d_in[13];
    const float* f_w1  = (const float*)d_in[14], *f_b1  = (const float*)d_in[15];
    const float* f_w2  = (const float*)d_in[16], *f_b2  = (const float*)d_in[17];
    const int* src = eidx;
    const int* dst = eidx + NE;
    float* out = (float*)d_out;

    const size_t BUF = (size_t)NN * HID;
    float* bA = (float*)d_ws;
    float* bB = bA + BUF;
    float* bC = bB + BUF;
    int* row_ptr  = (int*)(bC + BUF);        // NN+1
    int* cnt      = row_ptr + (NN + 1);      // NN (reused as fill cursor)
    int* esrc     = cnt + NN;                // NE
    int* partials = esrc + NE;               // SCAN_BLK

    const int nb8  = (NN + 7) / 8;            // 5000 (K=11 lin)
    const int nbm  = (NN + 127) / 128;        // 313 (mfma lin)
    const int eb   = (NE + 255) / 256;        // 2500
    const int gb   = (NN * 32 + 255) / 256;   // 5000
    const int hb   = (NN * 64 + 255) / 256;   // 10000

    // ---- CSR build ----
    (void)hipMemsetAsync(cnt, 0, NN * sizeof(int), stream);
    hist_kernel<<<eb, 256, 0, stream>>>(dst, cnt);
    scan1_kernel<<<SCAN_BLK, 256, 0, stream>>>(cnt, row_ptr, partials);
    scan2_kernel<<<1, 256, 0, stream>>>(partials, row_ptr);
    scan3_kernel<<<SCAN_BLK, 256, 0, stream>>>(row_ptr, partials);
    (void)hipMemsetAsync(cnt, 0, NN * sizeof(int), stream);
    fill_kernel<<<eb, 256, 0, stream>>>(src, dst, row_ptr, cnt, esrc);

    // ---- conv0 ----
    lin_kernel<11, true><<<nb8, 128, 0, stream>>>(x, c0_w1, c0_b1, bA, NN);
    gather_agg_kernel<<<gb, 256, 0, stream>>>(bA, row_ptr, esrc, bB);
    mfma_lin_kernel<1, true><<<nbm, 256, 0, stream>>>(bB, nullptr, c0_w2, c0_b2, bB);   // l1 = bB
    gather_agg_kernel<<<gb, 256, 0, stream>>>(bB, row_ptr, esrc, bC);
    mfma_lin_kernel<1, true><<<nbm, 256, 0, stream>>>(bC, nullptr, c0_w2, c0_b2, bC);   // l2 = bC
    mfma_lin_kernel<2, false><<<nbm, 256, 0, stream>>>(bB, bC, c0_w3, c0_b3, bA);       // conv0 out = bA

    // ---- conv1 ----
    mfma_lin_kernel<1, true><<<nbm, 256, 0, stream>>>(bA, nullptr, c1_w1, c1_b1, bA);   // h = bA
    gather_agg_kernel<<<gb, 256, 0, stream>>>(bA, row_ptr, esrc, bB);
    mfma_lin_kernel<1, true><<<nbm, 256, 0, stream>>>(bB, nullptr, c1_w2, c1_b2, bB);   // l1 = bB
    gather_agg_kernel<<<gb, 256, 0, stream>>>(bB, row_ptr, esrc, bC);
    mfma_lin_kernel<1, true><<<nbm, 256, 0, stream>>>(bC, nullptr, c1_w2, c1_b2, bC);   // l2 = bC
    mfma_lin_kernel<2, false><<<nbm, 256, 0, stream>>>(bB, bC, c1_w3, c1_b3, bA);       // conv1 out = bA

    // ---- head ----
    mfma_lin_kernel<1, true><<<nbm, 256, 0, stream>>>(bA, nullptr, f_w1, f_b1, bA);
    head_out_kernel<<<hb, 256, 0, stream>>>(bA, f_w2, f_b2, out);
}

// Round 7
// 557.156 us; speedup vs baseline: 8.9127x; 1.0383x over previous
//
#include <hip/hip_runtime.h>

#define NN 40000
#define NE 640000
#define HID 128
#define SCAN_BLK ((NN + 255) / 256)   // 157

typedef __attribute__((ext_vector_type(8)))  short short8;
typedef __attribute__((ext_vector_type(4)))  short short4v;
typedef __attribute__((ext_vector_type(16))) float floatx16;
typedef unsigned int uint;

__device__ __forceinline__ short f2bf(float f) {
    union { float f; unsigned u; } c; c.f = f;
    unsigned u = c.u;
    unsigned r = (u + 0x7FFF + ((u >> 16) & 1)) >> 16;   // RNE
    return (short)r;
}
__device__ __forceinline__ float bf2f(short h) {
    union { unsigned u; float f; } c;
    c.u = ((unsigned)(unsigned short)h) << 16;
    return c.f;
}
__device__ __forceinline__ float asf(uint u) {
    union { uint u; float f; } c; c.u = u; return c.f;
}
// Packed split-bf16: u32 = (hi_bf16 << 16) | lo_bf16; hi+lo ~ x to ~2^-17 rel.
__device__ __forceinline__ uint packsplit(float f) {
    short h = f2bf(f);
    short l = f2bf(f - bf2f(h));
    return ((uint)(unsigned short)h << 16) | (uint)(unsigned short)l;
}
__device__ __forceinline__ float unpackf(uint u) {
    return asf(u & 0xFFFF0000u) + asf(u << 16);
}

// ---------------- split-bf16 MFMA linear (packed activations/weights) ------
// out[N][128] = relu?( X · W^T + b ). X = PHASES blocks of 128 packed cols
// (X0, X1), row stride 128; W packed, [128][PHASES*128] row-major.
// acc += xh*wh + xl*wh + xh*wl (fp32 accum) -> fp32-grade result.
// Block: 256 thr = 4 waves; tile 128 rows x 128 cols; BK=64 per k-stage.
// In-place safe (out==X0): all X reads precede the epilogue store.
template<int PHASES, bool RELU, bool PACKOUT>
__global__ __launch_bounds__(256, 2) void mfma_lin_kernel(
    const uint* __restrict__ X0, const uint* __restrict__ X1,
    const uint* __restrict__ W, const float* __restrict__ b,
    uint* __restrict__ out)
{
    constexpr int LDK = 72;                  // 64 + 8 shorts (16B pad)
    __shared__ short sAh[128 * LDK];
    __shared__ short sAl[128 * LDK];
    __shared__ short sWh[128 * LDK];
    __shared__ short sWl[128 * LDK];

    const int t    = threadIdx.x;
    const int wave = t >> 6;
    const int lane = t & 63;
    const int r0   = blockIdx.x * 128;
    const int WS   = PHASES * 128;           // W row stride

    floatx16 acc[4];
    #pragma unroll
    for (int ct = 0; ct < 4; ++ct)
        #pragma unroll
        for (int i = 0; i < 16; ++i) acc[ct][i] = 0.f;

    const int m31  = lane & 31;
    const int half = lane >> 5;              // k-subchunk within K16
    const int aOff = (wave * 32 + m31) * LDK + half * 8;
    const int wOff = m31 * LDK + half * 8;

    for (int s = 0; s < 2 * PHASES; ++s) {   // k-stages of 64
        const int p     = s >> 1;
        const int xc0   = (s & 1) * 64;      // col offset within X row
        const int wc0   = p * 128 + xc0;     // col offset within W row
        const uint* Xp  = (PHASES == 2 && p == 1) ? X1 : X0;

        // stage X tile: 128 rows x 64 cols (2048 uint4, 8/thread)
        #pragma unroll
        for (int i = 0; i < 8; ++i) {
            int v   = t + 256 * i;
            int row = v >> 4;
            int c4  = (v & 15) * 4;
            int gr  = r0 + row;
            uint4 u = make_uint4(0u, 0u, 0u, 0u);
            if (gr < NN) u = *(const uint4*)(Xp + (size_t)gr * 128 + xc0 + c4);
            short4v hi, lo;
            hi.x = (short)(u.x >> 16); lo.x = (short)u.x;
            hi.y = (short)(u.y >> 16); lo.y = (short)u.y;
            hi.z = (short)(u.z >> 16); lo.z = (short)u.z;
            hi.w = (short)(u.w >> 16); lo.w = (short)u.w;
            *(short4v*)(sAh + row * LDK + c4) = hi;
            *(short4v*)(sAl + row * LDK + c4) = lo;
        }
        // stage W tile: 128 out-cols x 64 k-cols
        #pragma unroll
        for (int i = 0; i < 8; ++i) {
            int v   = t + 256 * i;
            int row = v >> 4;
            int c4  = (v & 15) * 4;
            uint4 u = *(const uint4*)(W + (size_t)row * WS + wc0 + c4);
            short4v hi, lo;
            hi.x = (short)(u.x >> 16); lo.x = (short)u.x;
            hi.y = (short)(u.y >> 16); lo.y = (short)u.y;
            hi.z = (short)(u.z >> 16); lo.z = (short)u.z;
            hi.w = (short)(u.w >> 16); lo.w = (short)u.w;
            *(short4v*)(sWh + row * LDK + c4) = hi;
            *(short4v*)(sWl + row * LDK + c4) = lo;
        }
        __syncthreads();

        #pragma unroll
        for (int kc = 0; kc < 4; ++kc) {     // 4 x K16
            short8 ah = *(const short8*)(sAh + aOff + kc * 16);
            short8 al = *(const short8*)(sAl + aOff + kc * 16);
            #pragma unroll
            for (int ct = 0; ct < 4; ++ct) {
                short8 bh = *(const short8*)(sWh + wOff + ct * 32 * LDK + kc * 16);
                short8 bl = *(const short8*)(sWl + wOff + ct * 32 * LDK + kc * 16);
                acc[ct] = __builtin_amdgcn_mfma_f32_32x32x16_bf16(ah, bh, acc[ct], 0, 0, 0);
                acc[ct] = __builtin_amdgcn_mfma_f32_32x32x16_bf16(al, bh, acc[ct], 0, 0, 0);
                acc[ct] = __builtin_amdgcn_mfma_f32_32x32x16_bf16(ah, bl, acc[ct], 0, 0, 0);
            }
        }
        __syncthreads();                     // guard LDS restage
    }

    // epilogue: bias + relu + pack + store.
    // C/D: col=lane&31, row=(reg&3)+8*(reg>>2)+4*half
    #pragma unroll
    for (int ct = 0; ct < 4; ++ct) {
        int col = ct * 32 + m31;
        float bias = b[col];
        #pragma unroll
        for (int reg = 0; reg < 16; ++reg) {
            int row = (reg & 3) + 8 * (reg >> 2) + 4 * half;
            int gr  = r0 + wave * 32 + row;
            if (gr < NN) {
                float v = acc[ct][reg] + bias;
                if (RELU) v = fmaxf(v, 0.f);
                if (PACKOUT) out[(size_t)gr * HID + col] = packsplit(v);
                else         ((float*)out)[(size_t)gr * HID + col] = v;
            }
        }
    }
}

// ---------------- fp32 linear for K=11 (first embed only), packs output ----
template<int K, bool RELU>
__global__ __launch_bounds__(128) void lin_kernel(
    const float* __restrict__ X, const float* __restrict__ W,
    const float* __restrict__ b, uint* __restrict__ out, int n_rows)
{
    constexpr int ROWS = 8;
    __shared__ float xs[ROWS * K];
    const int m  = threadIdx.x;
    const int r0 = blockIdx.x * ROWS;
    for (int i = threadIdx.x; i < ROWS * K; i += 128) {
        int r = i / K, k = i - r * K;
        int row = r0 + r;
        xs[i] = (row < n_rows) ? X[(size_t)row * K + k] : 0.f;
    }
    __syncthreads();
    float acc[ROWS] = {};
    const float* Wm = W + (size_t)m * K;
    for (int k = 0; k < K; ++k) {
        float w = Wm[k];
        #pragma unroll
        for (int r = 0; r < ROWS; ++r) acc[r] += xs[r * K + k] * w;
    }
    const float bias = b[m];
    #pragma unroll
    for (int r = 0; r < ROWS; ++r) {
        int row = r0 + r;
        if (row < n_rows) {
            float v = acc[r] + bias;
            if (RELU) v = fmaxf(v, 0.f);
            out[(size_t)row * HID + m] = packsplit(v);
        }
    }
}

// ---------------- weight pre-split (once per launch, 131072 elems) ----------
__global__ __launch_bounds__(256) void wprep_kernel(
    const float* __restrict__ w0, const float* __restrict__ w1,
    const float* __restrict__ w2, const float* __restrict__ w3,
    const float* __restrict__ w4, const float* __restrict__ w5,
    uint* __restrict__ wp)
{
    int i = blockIdx.x * 256 + threadIdx.x;
    if (i >= 131072) return;
    const float* src; int off;
    if      (i < 16384)  { src = w0; off = 0; }
    else if (i < 49152)  { src = w1; off = 16384; }
    else if (i < 65536)  { src = w2; off = 49152; }
    else if (i < 81920)  { src = w3; off = 65536; }
    else if (i < 114688) { src = w4; off = 81920; }
    else                 { src = w5; off = 114688; }
    wp[i] = packsplit(src[i - off]);
}

// ---------------- CSR build (by dst) ----------------
__global__ __launch_bounds__(256) void hist_kernel(
    const int* __restrict__ dst, int* __restrict__ cnt)
{
    int e = blockIdx.x * 256 + threadIdx.x;
    if (e < NE) atomicAdd(&cnt[dst[e]], 1);
}

__global__ __launch_bounds__(256) void scan1_kernel(
    const int* __restrict__ cnt, int* __restrict__ row_ptr,
    int* __restrict__ partials)
{
    __shared__ int s[256];
    const int t = threadIdx.x;
    const int i = blockIdx.x * 256 + t;
    int v = (i < NN) ? cnt[i] : 0;
    s[t] = v;
    __syncthreads();
    #pragma unroll
    for (int off = 1; off < 256; off <<= 1) {
        int x = (t >= off) ? s[t - off] : 0;
        __syncthreads();
        s[t] += x;
        __syncthreads();
    }
    if (i < NN) row_ptr[i] = s[t] - v;
    if (t == 255) partials[blockIdx.x] = s[255];
}

__global__ __launch_bounds__(256) void scan2_kernel(
    int* __restrict__ partials, int* __restrict__ row_ptr)
{
    __shared__ int s[256];
    const int t = threadIdx.x;
    int v = (t < SCAN_BLK) ? partials[t] : 0;
    s[t] = v;
    __syncthreads();
    #pragma unroll
    for (int off = 1; off < 256; off <<= 1) {
        int x = (t >= off) ? s[t - off] : 0;
        __syncthreads();
        s[t] += x;
        __syncthreads();
    }
    if (t < SCAN_BLK) partials[t] = s[t] - v;
    if (t == 255) row_ptr[NN] = s[255];
}

__global__ __launch_bounds__(256) void scan3_kernel(
    int* __restrict__ row_ptr, const int* __restrict__ partials)
{
    const int i = blockIdx.x * 256 + threadIdx.x;
    if (i < NN) row_ptr[i] += partials[blockIdx.x];
}

__global__ __launch_bounds__(256) void fill_kernel(
    const int* __restrict__ src, const int* __restrict__ dst,
    const int* __restrict__ row_ptr, int* __restrict__ pos,
    int* __restrict__ esrc)
{
    int e = blockIdx.x * 256 + threadIdx.x;
    if (e >= NE) return;
    int d = dst[e];
    int p = row_ptr[d] + atomicAdd(&pos[d], 1);
    esrc[p] = src[e];
}

// ---------------- Gather aggregation (packed in/out, unroll x2) -------------
__global__ __launch_bounds__(256) void gather_agg_kernel(
    const uint* __restrict__ h, const int* __restrict__ row_ptr,
    const int* __restrict__ esrc, uint* __restrict__ agg)
{
    int t = blockIdx.x * 256 + threadIdx.x;
    int node = t >> 5;
    int c4   = t & 31;
    if (node >= NN) return;
    const int lo = row_ptr[node], hi = row_ptr[node + 1];
    float4 aH = make_float4(0,0,0,0), aL = make_float4(0,0,0,0);
    float4 bH = make_float4(0,0,0,0), bL = make_float4(0,0,0,0);
    int e = lo;
    for (; e + 2 <= hi; e += 2) {
        int s0 = esrc[e], s1 = esrc[e + 1];
        uint4 u0 = *(const uint4*)(h + (size_t)s0 * HID + c4 * 4);
        uint4 u1 = *(const uint4*)(h + (size_t)s1 * HID + c4 * 4);
        aH.x += asf(u0.x & 0xFFFF0000u); aL.x += asf(u0.x << 16);
        aH.y += asf(u0.y & 0xFFFF0000u); aL.y += asf(u0.y << 16);
        aH.z += asf(u0.z & 0xFFFF0000u); aL.z += asf(u0.z << 16);
        aH.w += asf(u0.w & 0xFFFF0000u); aL.w += asf(u0.w << 16);
        bH.x += asf(u1.x & 0xFFFF0000u); bL.x += asf(u1.x << 16);
        bH.y += asf(u1.y & 0xFFFF0000u); bL.y += asf(u1.y << 16);
        bH.z += asf(u1.z & 0xFFFF0000u); bL.z += asf(u1.z << 16);
        bH.w += asf(u1.w & 0xFFFF0000u); bL.w += asf(u1.w << 16);
    }
    if (e < hi) {
        int s0 = esrc[e];
        uint4 u0 = *(const uint4*)(h + (size_t)s0 * HID + c4 * 4);
        aH.x += asf(u0.x & 0xFFFF0000u); aL.x += asf(u0.x << 16);
        aH.y += asf(u0.y & 0xFFFF0000u); aL.y += asf(u0.y << 16);
        aH.z += asf(u0.z & 0xFFFF0000u); aL.z += asf(u0.z << 16);
        aH.w += asf(u0.w & 0xFFFF0000u); aL.w += asf(u0.w << 16);
    }
    uint4 o;
    o.x = packsplit((aH.x + bH.x) + (aL.x + bL.x));
    o.y = packsplit((aH.y + bH.y) + (aL.y + bL.y));
    o.z = packsplit((aH.z + bH.z) + (aL.z + bL.z));
    o.w = packsplit((aH.w + bH.w) + (aL.w + bL.w));
    *(uint4*)(agg + (size_t)node * HID + c4 * 4) = o;
}

// ---------------- Head ----------------
__global__ __launch_bounds__(256) void head_out_kernel(
    const uint* __restrict__ h, const float* __restrict__ w,
    const float* __restrict__ b, float* __restrict__ out)
{
    long long t = (long long)blockIdx.x * blockDim.x + threadIdx.x;
    int node = (int)(t >> 6);
    int lane = threadIdx.x & 63;
    if (node >= NN) return;
    const uint* hr = h + (size_t)node * HID;
    float a = unpackf(hr[lane]) * w[lane] + unpackf(hr[64 + lane]) * w[64 + lane];
    #pragma unroll
    for (int off = 32; off > 0; off >>= 1) a += __shfl_down(a, off);
    if (lane == 0) out[node] = a + b[0];
}

extern "C" void kernel_launch(void* const* d_in, const int* in_sizes, int n_in,
                              void* d_out, int out_size, void* d_ws, size_t ws_size,
                              hipStream_t stream)
{
    const float* x     = (const float*)d_in[0];
    const int*   eidx  = (const int*)d_in[1];
    const float* c0_w1 = (const float*)d_in[2],  *c0_b1 = (const float*)d_in[3];
    const float* c0_w2 = (const float*)d_in[4],  *c0_b2 = (const float*)d_in[5];
    const float* c0_w3 = (const float*)d_in[6],  *c0_b3 = (const float*)d_in[7];
    const float* c1_w1 = (const float*)d_in[8],  *c1_b1 = (const float*)d_in[9];
    const float* c1_w2 = (const float*)d_in[10], *c1_b2 = (const float*)d_in[11];
    const float* c1_w3 = (const float*)d_in[12], *c1_b3 = (const float*)d_in[13];
    const float* f_w1  = (const float*)d_in[14], *f_b1  = (const float*)d_in[15];
    const float* f_w2  = (const float*)d_in[16], *f_b2  = (const float*)d_in[17];
    const int* src = eidx;
    const int* dst = eidx + NE;
    float* out = (float*)d_out;

    const size_t BUF = (size_t)NN * HID;
    uint* bA = (uint*)d_ws;
    uint* bB = bA + BUF;
    uint* bC = bB + BUF;
    int* row_ptr  = (int*)(bC + BUF);        // NN+1
    int* cnt      = row_ptr + (NN + 1);      // NN (reused as fill cursor)
    int* esrc     = cnt + NN;                // NE
    int* partials = esrc + NE;               // SCAN_BLK
    uint* wp      = (uint*)(partials + SCAN_BLK);  // 131072 packed weights

    // packed-weight offsets in wp
    uint* p_c0w2 = wp + 0;
    uint* p_c0w3 = wp + 16384;
    uint* p_c1w1 = wp + 49152;
    uint* p_c1w2 = wp + 65536;
    uint* p_c1w3 = wp + 81920;
    uint* p_fw1  = wp + 114688;

    const int nb8  = (NN + 7) / 8;            // 5000 (K=11 lin)
    const int nbm  = (NN + 127) / 128;        // 313 (mfma lin)
    const int eb   = (NE + 255) / 256;        // 2500
    const int gb   = (NN * 32 + 255) / 256;   // 5000
    const int hb   = (NN * 64 + 255) / 256;   // 10000

    // ---- weight prep + CSR build ----
    wprep_kernel<<<512, 256, 0, stream>>>(c0_w2, c0_w3, c1_w1, c1_w2, c1_w3, f_w1, wp);
    (void)hipMemsetAsync(cnt, 0, NN * sizeof(int), stream);
    hist_kernel<<<eb, 256, 0, stream>>>(dst, cnt);
    scan1_kernel<<<SCAN_BLK, 256, 0, stream>>>(cnt, row_ptr, partials);
    scan2_kernel<<<1, 256, 0, stream>>>(partials, row_ptr);
    scan3_kernel<<<SCAN_BLK, 256, 0, stream>>>(row_ptr, partials);
    (void)hipMemsetAsync(cnt, 0, NN * sizeof(int), stream);
    fill_kernel<<<eb, 256, 0, stream>>>(src, dst, row_ptr, cnt, esrc);

    // ---- conv0 ----
    lin_kernel<11, true><<<nb8, 128, 0, stream>>>(x, c0_w1, c0_b1, bA, NN);
    gather_agg_kernel<<<gb, 256, 0, stream>>>(bA, row_ptr, esrc, bB);
    mfma_lin_kernel<1, true, true><<<nbm, 256, 0, stream>>>(bB, nullptr, p_c0w2, c0_b2, bB);
    gather_agg_kernel<<<gb, 256, 0, stream>>>(bB, row_ptr, esrc, bC);
    mfma_lin_kernel<1, true, true><<<nbm, 256, 0, stream>>>(bC, nullptr, p_c0w2, c0_b2, bC);
    mfma_lin_kernel<2, false, true><<<nbm, 256, 0, stream>>>(bB, bC, p_c0w3, c0_b3, bA);

    // ---- conv1 ----
    mfma_lin_kernel<1, true, true><<<nbm, 256, 0, stream>>>(bA, nullptr, p_c1w1, c1_b1, bA);
    gather_agg_kernel<<<gb, 256, 0, stream>>>(bA, row_ptr, esrc, bB);
    mfma_lin_kernel<1, true, true><<<nbm, 256, 0, stream>>>(bB, nullptr, p_c1w2, c1_b2, bB);
    gather_agg_kernel<<<gb, 256, 0, stream>>>(bB, row_ptr, esrc, bC);
    mfma_lin_kernel<1, true, true><<<nbm, 256, 0, stream>>>(bC, nullptr, p_c1w2, c1_b2, bC);
    mfma_lin_kernel<2, false, true><<<nbm, 256, 0, stream>>>(bB, bC, p_c1w3, c1_b3, bA);

    // ---- head ----
    mfma_lin_kernel<1, true, true><<<nbm, 256, 0, stream>>>(bA, nullptr, p_fw1, f_b1, bA);
    head_out_kernel<<<hb, 256, 0, stream>>>(bA, f_w2, f_b2, out);
}